// Round 8
// baseline (1659.719 us; speedup 1.0000x reference)
//
#include <hip/hip_runtime.h>
#include <stdint.h>

typedef float  f32x4 __attribute__((ext_vector_type(4)));
typedef _Float16 f16x8 __attribute__((ext_vector_type(8)));
typedef _Float16 f16x4 __attribute__((ext_vector_type(4)));

// ws layout (half units)
#define OFF_We1T 0          // [768][1024]  (k baked)
#define OFF_We2T 786432     // [256][768]   (k baked)
#define OFF_WqT  983040     // [256][256] head-permuted cols, k baked
#define OFF_WpeT 1048576    // [256][256] head-permuted cols, k baked
#define OFF_WvT  1114112    // [256][256]   (k baked)
#define OFF_A1T  1179648    // [64][64]     (k baked)
#define OFF_A2T  1183744    // [32][64]     (k baked)
#define NHALF    1185792

__device__ __forceinline__ void gl_lds16(const void* g, void* l) {
  __builtin_amdgcn_global_load_lds((const __attribute__((address_space(1))) uint32_t*)g,
                                   (__attribute__((address_space(3))) uint32_t*)l, 16, 0, 0);
}

// 16B-granule XOR swizzle within each 64-half K-block: stored granule =
// logical granule ^ (row&7). Involution; baked into weight/h/xin storage so
// linear global_load_lds lands pre-swizzled; MFMA reads XOR with (row&7).
__device__ __forceinline__ int bake(int k, int n) {
  return (k & ~63) | ((((k >> 3) ^ n) & 7) << 3) | (k & 7);
}

__global__ __launch_bounds__(256) void prep_weights(
    const float* We1, const float* We2, const float* Wq, const float* Wpe,
    const float* Wv, const float* A1, const float* A2,
    const float* bq, const float* bpe,
    _Float16* wsh, float* bqp, float* bpep) {
  int i = blockIdx.x * 256 + threadIdx.x;
  if (i < OFF_We2T) {                       // We1T[n][k] = We1[bake(k)][n]
    int n = i >> 10, k = i & 1023;
    wsh[i] = (_Float16)We1[bake(k, n) * 768 + n];
  } else if (i < OFF_WqT) {                 // We2T[256][768]
    int j = i - OFF_We2T; int n = j / 768, k = j - n * 768;
    wsh[i] = (_Float16)We2[bake(k, n) * 256 + n];
  } else if (i < OFF_WpeT) {                // WqT' : col n=h*32+c <- src col c*8+h
    int j = i - OFF_WqT; int n = j >> 8, k = j & 255;
    int sc = ((n & 31) << 3) + (n >> 5);
    wsh[i] = (_Float16)Wq[bake(k, n) * 256 + sc];
  } else if (i < OFF_WvT) {
    int j = i - OFF_WpeT; int n = j >> 8, k = j & 255;
    int sc = ((n & 31) << 3) + (n >> 5);
    wsh[i] = (_Float16)Wpe[bake(k, n) * 256 + sc];
  } else if (i < OFF_A1T) {
    int j = i - OFF_WvT; int n = j >> 8, k = j & 255;
    wsh[i] = (_Float16)Wv[bake(k, n) * 256 + n];
  } else if (i < OFF_A2T) {                 // A1T[o][c] = A1[bake(c)][o]
    int j = i - OFF_A1T; int o = j >> 6, c = j & 63;
    wsh[i] = (_Float16)A1[bake(c, o) * 64 + o];
  } else if (i < NHALF) {                   // A2T[o][c] = A2[bake(c)][o]
    int j = i - OFF_A2T; int o = j >> 6, c = j & 63;
    wsh[i] = (_Float16)A2[bake(c, o) * 32 + o];
  } else if (i < NHALF + 256) {
    int j = i - NHALF;
    bqp[j] = bq[((j & 31) << 3) + (j >> 5)];
  } else if (i < NHALF + 512) {
    int j = i - NHALF - 256;
    bpep[j] = bpe[((j & 31) << 3) + (j >> 5)];
  }
}

__global__ __launch_bounds__(256) void prep_dw(const float* s, const float* d,
                                               float* dw, float* fw, int N) {
  int n = blockIdx.x * 256 + threadIdx.x;
  if (n >= N) return;
  float dx = s[3*n] - d[3*n], dy = s[3*n+1] - d[3*n+1], dz = s[3*n+2] - d[3*n+2];
  float d2 = dx*dx + dy*dy + dz*dz;
  float w = expf(-0.5f * d2);
  dw[n] = w;
  fw[n] = w / (w + 1e-10f);   // == weights_avg.sum(axis=1) exactly
}

struct GP {
  const float* q; const float* e; const float* v; const float* rev;
  const _Float16* wsh;
  const float* be1; const float* be2; const float* bv;
  const float* bqp; const float* bpep;
  const float* dw; const float* fw;
  float* outb;
  int N; int SPLIT;
};

// MODE 0: h = relu(concat(q,e,rev,v) @ We1 + be1)   -> fp16 stash (baked) in d_out
// MODE 1: EF = (h @ We2 + be2) * dw                 -> fp32 out
// MODE 2: nb/2==0: qh -> xin(baked) ; ==1: eh -> xin ; ==2: x = fw*(v@Wv+bv)
// Single-buffered m97 structure: 2 barriers/K-step, ~35.8 KB LDS -> 4 blocks/CU.
template <int MODE>
__global__ __launch_bounds__(256, 4) void gemm_k(GP p) {
  __shared__ __align__(16) _Float16 smh[2][8704];   // A=smh[0], B=smh[1]; epilogue arena = all 34816 B
  __shared__ float biasL[128];
  __shared__ float scaleL[128];
  const int t = threadIdx.x;
  const int w = t >> 6, lane = t & 63, lr = lane & 15, lk = lane >> 4;
  // ---- XCD-aware bijective remap (grid.y padded %8==0; xcd = flat%8 owns a
  // contiguous mb chunk with its nb's consecutive -> A-panel reads hit ONE L2)
  const int NBX = (MODE == 1) ? 2 : 6;
  const int flat = blockIdx.y * NBX + blockIdx.x;
  const int xcd = flat & 7, kk2 = flat >> 3;
  const int CH = gridDim.y >> 3;
  const int nb = kk2 % NBX;
  const int mb = xcd * CH + kk2 / NBX;
  const int N = p.N, SPLIT = p.SPLIT;
  const int MT = (N + 127) >> 7;
  if (mb >= MT) return;
  const int wrow = (w >> 1) * 64, wcol = (w & 1) * 64;
  float* Xf  = p.outb;
  float* EFf = p.outb + (size_t)N * 256;
  float* PRf = p.outb + (size_t)N * 512;
  _Float16* hp1 = (_Float16*)Xf;     // h rows [0, SPLIT)
  _Float16* hp2 = (_Float16*)PRf;    // h rows [SPLIT, N) ; later xin lives here

  int K, KT; size_t boff; int g = 0, nbl = nb;
  if (MODE == 0)      { K = 1024; KT = 16; boff = (size_t)nb * 128 * 1024; }
  else if (MODE == 1) { K = 768;  KT = 12; boff = OFF_We2T + (size_t)nb * 128 * 768; }
  else { K = 256; KT = 4; g = nb >> 1; nbl = nb & 1;
         size_t wb = (g == 0) ? (size_t)OFF_WqT : (g == 1) ? (size_t)OFF_WpeT : (size_t)OFF_WvT;
         boff = wb + (size_t)nbl * 128 * 256; }
  const _Float16* Bt = p.wsh + boff;

  if (t < 128) {
    int gr = mb * 128 + t; if (gr > N - 1) gr = N - 1;
    if (MODE == 0) biasL[t] = p.be1[nb * 128 + t];
    else if (MODE == 1) { biasL[t] = p.be2[nb * 128 + t]; scaleL[t] = p.dw[gr]; }
    else {
      if (g == 0)      biasL[t] = p.bqp[nbl * 128 + t];
      else if (g == 1) biasL[t] = p.bpep[nbl * 128 + t];
      else { biasL[t] = p.bv[nbl * 128 + t]; scaleL[t] = p.fw[gr]; }
    }
  }

  auto stageB = [&](int kt) {
#pragma unroll
    for (int i = 0; i < 4; ++i)
      gl_lds16(Bt + (size_t)(i * 32 + (t >> 3)) * K + kt * 64 + (t & 7) * 8,
               (char*)smh[1] + i * 4096 + w * 1024);
  };
  auto stageA_dma = [&](int kt) {   // MODE 1 only: h is pre-baked fp16
    const _Float16* hr = (mb * 128 < SPLIT)
        ? hp1 + (size_t)mb * 128 * 768
        : hp2 + (size_t)(mb * 128 - SPLIT) * 768;
    int rmax = N - 1 - mb * 128;
#pragma unroll
    for (int i = 0; i < 4; ++i) {
      int rl = i * 32 + (t >> 3); if (rl > rmax) rl = rmax;
      gl_lds16(hr + (size_t)rl * 768 + kt * 64 + (t & 7) * 8,
               (char*)smh[0] + i * 4096 + w * 1024);
    }
  };
  auto loadA = [&](int kt, float4* pre) {    // fp32 sources, issue early (T14)
    const float* As; int cc0;
    if (MODE == 0) {
      int gg = kt >> 2;   // concat order: query, edge, reverse_edge, value
      As = (gg == 0) ? p.q : (gg == 1) ? p.e : (gg == 2) ? p.rev : p.v;
      cc0 = (kt & 3) * 64;
    } else {
      As = (g == 0) ? p.q : (g == 1) ? p.e : p.v; cc0 = kt * 64;
    }
#pragma unroll
    for (int i = 0; i < 8; ++i) {
      int id = i * 256 + t, row = id >> 4, c4 = id & 15;
      int gr = mb * 128 + row; if (gr > N - 1) gr = N - 1;
      pre[i] = *(const float4*)(As + (size_t)gr * 256 + cc0 + c4 * 4);
    }
  };
  auto writeA = [&](const float4* pre) {  // cvt + swizzled ds_write
#pragma unroll
    for (int i = 0; i < 8; ++i) {
      int id = i * 256 + t, row = id >> 4, c4 = id & 15;
      f16x4 hv; hv.x = (_Float16)pre[i].x; hv.y = (_Float16)pre[i].y;
      hv.z = (_Float16)pre[i].z; hv.w = (_Float16)pre[i].w;
      int off = row * 64 + (((((c4 >> 1) ^ row) & 7) << 3) | ((c4 & 1) << 2));
      *(f16x4*)(&smh[0][off]) = hv;
    }
  };

  f32x4 acc[4][4] = {};
  float4 pre[8];
  // prologue: stage tile 0
  if (MODE == 1) stageA_dma(0);
  else { loadA(0, pre); writeA(pre); }
  stageB(0);
  __syncthreads();

  for (int kt = 0; kt < KT; ++kt) {
    const bool more = (kt + 1 < KT);
    if (more && MODE != 1) loadA(kt + 1, pre);   // fire next A loads before MFMAs
#pragma unroll
    for (int ks = 0; ks < 2; ++ks) {
      f16x8 af[4], bf[4];
#pragma unroll
      for (int i = 0; i < 4; ++i)
        af[i] = *(const f16x8*)(smh[0] + (wrow + i * 16 + lr) * 64 + (((ks * 4 + lk) ^ (lr & 7)) << 3));
#pragma unroll
      for (int j = 0; j < 4; ++j)
        bf[j] = *(const f16x8*)(smh[1] + (wcol + j * 16 + lr) * 64 + (((ks * 4 + lk) ^ (lr & 7)) << 3));
#pragma unroll
      for (int i = 0; i < 4; ++i)
#pragma unroll
        for (int j = 0; j < 4; ++j)
          acc[i][j] = __builtin_amdgcn_mfma_f32_16x16x32_f16(af[i], bf[j], acc[i][j], 0, 0, 0);
    }
    if (more) {
      __syncthreads();                 // all reads of tile kt done
      if (MODE == 1) stageA_dma(kt + 1);
      else writeA(pre);                // loads had the MFMA phase to land
      stageB(kt + 1);
      __syncthreads();                 // tile kt+1 visible
    }
  }
  __syncthreads();   // protect smh reuse by epilogue

  // ---------------- epilogue (LDS transpose for packed stores) ----------------
  const bool f16out = (MODE == 0) || (MODE == 2 && g < 2);
  if (f16out) {
    _Float16* Cl = (_Float16*)smh;  // [128][136] padded = 34816 B exact
#pragma unroll
    for (int i = 0; i < 4; ++i)
#pragma unroll
      for (int j = 0; j < 4; ++j)
#pragma unroll
        for (int ii = 0; ii < 4; ++ii) {
          int r = wrow + i * 16 + lk * 4 + ii, c = wcol + j * 16 + lr;
          float val = acc[i][j][ii] + biasL[c];
          if (MODE == 0) val = fmaxf(val, 0.f);
          Cl[r * 136 + c] = (_Float16)val;
        }
    __syncthreads();
#pragma unroll
    for (int i = 0; i < 8; ++i) {
      int id = i * 256 + t, row = id >> 4, ch = id & 15;
      int gr = mb * 128 + row;
      if (gr < N) {
        f16x8 val = *(const f16x8*)(Cl + row * 136 + ch * 8);
        if (MODE == 0) {
          // h stored BAKED: granule (ch&7) ^ (gr&7) within its 64-half block
          _Float16* hrow = (gr < SPLIT) ? hp1 + (size_t)gr * 768
                                        : hp2 + (size_t)(gr - SPLIT) * 768;
          int b64 = nb * 128 + ((ch >> 3) << 6);
          *(f16x8*)(hrow + b64 + (((ch ^ gr) & 7) << 3)) = val;
        } else {
          // xin stored BAKED for attn: row = gr*8+q, logical granule G at G^(q&7)
          int j0 = nbl * 128 + ch * 8;
          int q = j0 >> 5;                                   // 0..7
          int G = ((j0 >> 3) & 3) | ((g == 1) ? 4 : 0);
          *(f16x8*)(hp2 + ((size_t)gr * 8 + q) * 64 + (((G ^ q) & 7) << 3)) = val;
        }
      }
    }
  } else {
    float* Cf = (float*)smh;  // [64][132] padded = 33792 B, two passes
#pragma unroll
    for (int pp = 0; pp < 2; ++pp) {
      __syncthreads();
      if ((w >> 1) == pp) {
#pragma unroll
        for (int i = 0; i < 4; ++i)
#pragma unroll
          for (int j = 0; j < 4; ++j)
#pragma unroll
            for (int ii = 0; ii < 4; ++ii) {
              int rl = i * 16 + lk * 4 + ii, c = wcol + j * 16 + lr;
              Cf[rl * 132 + c] = (acc[i][j][ii] + biasL[c]) * scaleL[pp * 64 + rl];
            }
      }
      __syncthreads();
#pragma unroll
      for (int i = 0; i < 8; ++i) {
        int id = i * 256 + t, row = id >> 5, ch = id & 31;
        int gr = mb * 128 + pp * 64 + row;
        if (gr < N) {
          float4 val = *(const float4*)(Cf + row * 132 + ch * 4);
          float* dst = (MODE == 1) ? EFf + (size_t)gr * 256 + nb * 128 + ch * 4
                                   : Xf  + (size_t)gr * 256 + nbl * 128 + ch * 4;
          *(float4*)dst = val;
        }
      }
    }
  }
}

// per-head MLP + softmax; 64 (n,h)-rows per block; xin (baked) read & prob written in place
__global__ __launch_bounds__(256) void attn_k(GP p, const float* a1, const float* a2) {
  __shared__ __align__(16) char sm[28928];
  _Float16* xinl = (_Float16*)sm;            // [64][64] baked, later h2 (swizzled)
  _Float16* A1l  = (_Float16*)(sm + 8192);   // baked
  _Float16* A2l  = (_Float16*)(sm + 16384);  // baked
  float*    lg   = (float*)(sm + 20480);     // [64][33]
  const int t = threadIdx.x;
  const int w = t >> 6, lane = t & 63, lr = lane & 15, lk = lane >> 4;
  const int N = p.N;
  float* PRf = p.outb + (size_t)N * 512;
  const _Float16* xing = (const _Float16*)PRf;
  size_t rowbase = (size_t)blockIdx.x * 64;

#pragma unroll
  for (int i = 0; i < 2; ++i)
    gl_lds16(xing + (rowbase + i * 32 + (t >> 3)) * 64 + (t & 7) * 8,
             sm + i * 4096 + w * 1024);
#pragma unroll
  for (int i = 0; i < 2; ++i)
    gl_lds16(p.wsh + OFF_A1T + (size_t)(i * 32 + (t >> 3)) * 64 + (t & 7) * 8,
             sm + 8192 + i * 4096 + w * 1024);
  gl_lds16(p.wsh + OFF_A2T + (size_t)(t >> 3) * 64 + (t & 7) * 8,
           sm + 16384 + w * 1024);
  __syncthreads();

  f32x4 acc1[4] = {};
#pragma unroll
  for (int ks = 0; ks < 2; ++ks) {
    f16x8 a = *(const f16x8*)(xinl + (w * 16 + lr) * 64 + (((ks * 4 + lk) ^ (lr & 7)) << 3));
#pragma unroll
    for (int j = 0; j < 4; ++j) {
      f16x8 b = *(const f16x8*)(A1l + (j * 16 + lr) * 64 + (((ks * 4 + lk) ^ (lr & 7)) << 3));
      acc1[j] = __builtin_amdgcn_mfma_f32_16x16x32_f16(a, b, acc1[j], 0, 0, 0);
    }
  }
  __syncthreads();   // xinl reads done; overwrite with h2 (swizzled store)
#pragma unroll
  for (int j = 0; j < 4; ++j) {
    float bb = a1[j * 16 + lr];
#pragma unroll
    for (int ii = 0; ii < 4; ++ii) {
      float hv = fmaxf(acc1[j][ii] + bb, 0.f);
      int row2 = w * 16 + lk * 4 + ii, col = j * 16 + lr;
      xinl[row2 * 64 + (((((col >> 3) ^ row2) & 7) << 3) | (col & 7))] = (_Float16)hv;
    }
  }
  __syncthreads();
  f32x4 acc2[2] = {};
#pragma unroll
  for (int ks = 0; ks < 2; ++ks) {
    f16x8 a = *(const f16x8*)(xinl + (w * 16 + lr) * 64 + (((ks * 4 + lk) ^ (lr & 7)) << 3));
#pragma unroll
    for (int j = 0; j < 2; ++j) {
      f16x8 b = *(const f16x8*)(A2l + (j * 16 + lr) * 64 + (((ks * 4 + lk) ^ (lr & 7)) << 3));
      acc2[j] = __builtin_amdgcn_mfma_f32_16x16x32_f16(a, b, acc2[j], 0, 0, 0);
    }
  }
#pragma unroll
  for (int j = 0; j < 2; ++j) {
    float bb = a2[j * 16 + lr];
#pragma unroll
    for (int ii = 0; ii < 4; ++ii)
      lg[(w * 16 + lk * 4 + ii) * 33 + j * 16 + lr] = acc2[j][ii] + bb;
  }
  __syncthreads();
  {   // softmax over 32 channels; 4 lanes per row
    int r = t >> 2, pq = t & 3;
    float vv[8];
#pragma unroll
    for (int jj = 0; jj < 8; ++jj) vv[jj] = lg[r * 33 + pq * 8 + jj];
    float mx = vv[0];
#pragma unroll
    for (int jj = 1; jj < 8; ++jj) mx = fmaxf(mx, vv[jj]);
    mx = fmaxf(mx, __shfl_xor(mx, 1));
    mx = fmaxf(mx, __shfl_xor(mx, 2));
    float s = 0.f;
#pragma unroll
    for (int jj = 0; jj < 8; ++jj) { vv[jj] = __expf(vv[jj] - mx); s += vv[jj]; }
    s += __shfl_xor(s, 1);
    s += __shfl_xor(s, 2);
    float inv = 1.f / s;
#pragma unroll
    for (int jj = 0; jj < 8; ++jj) lg[r * 33 + pq * 8 + jj] = vv[jj] * inv;
  }
  __syncthreads();
  // write prob[n][o][h] coalesced (address == rowbase*32 + id, fully linear)
#pragma unroll
  for (int i = 0; i < 8; ++i) {
    int id = i * 256 + t; int hh = id & 7, o = (id >> 3) & 31, nl = id >> 8;
    PRf[(rowbase / 8 + nl) * 256 + o * 8 + hh] = lg[(nl * 8 + hh) * 33 + o];
  }
}

extern "C" void kernel_launch(void* const* d_in, const int* in_sizes, int n_in,
                              void* d_out, int out_size, void* d_ws, size_t ws_size,
                              hipStream_t stream) {
  const float* query = (const float*)d_in[0];
  const float* edge  = (const float*)d_in[1];
  const float* value = (const float*)d_in[2];
  const float* rev   = (const float*)d_in[3];
  const float* srcc  = (const float*)d_in[4];
  const float* dstc  = (const float*)d_in[5];
  const float* We1 = (const float*)d_in[6];  const float* be1 = (const float*)d_in[7];
  const float* We2 = (const float*)d_in[8];  const float* be2 = (const float*)d_in[9];
  const float* Wq  = (const float*)d_in[10]; const float* bq  = (const float*)d_in[11];
  const float* Wpe = (const float*)d_in[12]; const float* bpe = (const float*)d_in[13];
  const float* Wv  = (const float*)d_in[14]; const float* bv  = (const float*)d_in[15];
  const float* A1  = (const float*)d_in[16]; const float* a1  = (const float*)d_in[17];
  const float* A2  = (const float*)d_in[18]; const float* a2  = (const float*)d_in[19];
  const int N = in_sizes[0] / 256;           // 120000

  _Float16* wsh = (_Float16*)d_ws;
  float* wsf = (float*)d_ws;
  float* dwA  = wsf + NHALF / 2;
  float* fwA  = dwA + N;
  float* bqp  = fwA + N;
  float* bpep = bqp + 256;

  prep_weights<<<(NHALF + 512 + 255) / 256, 256, 0, stream>>>(
      We1, We2, Wq, Wpe, Wv, A1, A2, bq, bpe, wsh, bqp, bpep);
  prep_dw<<<(N + 255) / 256, 256, 0, stream>>>(srcc, dstc, dwA, fwA, N);

  GP p;
  p.q = query; p.e = edge; p.v = value; p.rev = rev;
  p.wsh = wsh; p.be1 = be1; p.be2 = be2; p.bv = bv;
  p.bqp = bqp; p.bpep = bpep; p.dw = dwA; p.fw = fwA;
  p.outb = (float*)d_out; p.N = N; p.SPLIT = (N * 2) / 3;

  const int MT = (N + 127) >> 7;             // 938
  const int MTP = (MT + 7) & ~7;             // 944: grid %8==0 for XCD remap
  gemm_k<0><<<dim3(6, MTP), 256, 0, stream>>>(p);   // h (fp16 baked, stashed in d_out)
  gemm_k<1><<<dim3(2, MTP), 256, 0, stream>>>(p);   // edge_feature
  gemm_k<2><<<dim3(6, MTP), 256, 0, stream>>>(p);   // x  +  xin (qh|eh, baked)
  attn_k<<<N / 8, 256, 0, stream>>>(p, a1, a2);     // prob
}

// Round 9
// 1269.545 us; speedup vs baseline: 1.3073x; 1.3073x over previous
//
#include <hip/hip_runtime.h>
#include <stdint.h>

typedef float  f32x4 __attribute__((ext_vector_type(4)));
typedef _Float16 f16x8 __attribute__((ext_vector_type(8)));
typedef _Float16 f16x4 __attribute__((ext_vector_type(4)));

// ws layout (half units)
#define OFF_We1T 0          // [768][1024]  (k baked)
#define OFF_We2T 786432     // [256][768]   (k baked)
#define OFF_WqT  983040     // [256][256] head-permuted cols, k baked
#define OFF_WpeT 1048576    // [256][256] head-permuted cols, k baked
#define OFF_WvT  1114112    // [256][256]   (k baked)
#define OFF_A1T  1179648    // [64][64]     (k baked)
#define OFF_A2T  1183744    // [32][64]     (k baked)
#define NHALF    1185792

__device__ __forceinline__ void gl_lds16(const void* g, void* l) {
  __builtin_amdgcn_global_load_lds((const __attribute__((address_space(1))) uint32_t*)g,
                                   (__attribute__((address_space(3))) uint32_t*)l, 16, 0, 0);
}

// 16B-granule XOR swizzle within each 64-half K-block: stored granule =
// logical granule ^ (row&7). Involution; sub-block-64, so valid for any BK
// that is a multiple of 64. Baked into weight/h/xin storage so linear
// global_load_lds lands pre-swizzled; MFMA reads XOR with (row&7).
__device__ __forceinline__ int bake(int k, int n) {
  return (k & ~63) | ((((k >> 3) ^ n) & 7) << 3) | (k & 7);
}

__global__ __launch_bounds__(256) void prep_weights(
    const float* We1, const float* We2, const float* Wq, const float* Wpe,
    const float* Wv, const float* A1, const float* A2,
    const float* bq, const float* bpe,
    _Float16* wsh, float* bqp, float* bpep) {
  int i = blockIdx.x * 256 + threadIdx.x;
  if (i < OFF_We2T) {                       // We1T[n][k] = We1[bake(k)][n]
    int n = i >> 10, k = i & 1023;
    wsh[i] = (_Float16)We1[bake(k, n) * 768 + n];
  } else if (i < OFF_WqT) {                 // We2T[256][768]
    int j = i - OFF_We2T; int n = j / 768, k = j - n * 768;
    wsh[i] = (_Float16)We2[bake(k, n) * 256 + n];
  } else if (i < OFF_WpeT) {                // WqT' : col n=h*32+c <- src col c*8+h
    int j = i - OFF_WqT; int n = j >> 8, k = j & 255;
    int sc = ((n & 31) << 3) + (n >> 5);
    wsh[i] = (_Float16)Wq[bake(k, n) * 256 + sc];
  } else if (i < OFF_WvT) {
    int j = i - OFF_WpeT; int n = j >> 8, k = j & 255;
    int sc = ((n & 31) << 3) + (n >> 5);
    wsh[i] = (_Float16)Wpe[bake(k, n) * 256 + sc];
  } else if (i < OFF_A1T) {
    int j = i - OFF_WvT; int n = j >> 8, k = j & 255;
    wsh[i] = (_Float16)Wv[bake(k, n) * 256 + n];
  } else if (i < OFF_A2T) {                 // A1T[o][c] = A1[bake(c)][o]
    int j = i - OFF_A1T; int o = j >> 6, c = j & 63;
    wsh[i] = (_Float16)A1[bake(c, o) * 64 + o];
  } else if (i < NHALF) {                   // A2T[o][c] = A2[bake(c)][o]
    int j = i - OFF_A2T; int o = j >> 6, c = j & 63;
    wsh[i] = (_Float16)A2[bake(c, o) * 32 + o];
  } else if (i < NHALF + 256) {
    int j = i - NHALF;
    bqp[j] = bq[((j & 31) << 3) + (j >> 5)];
  } else if (i < NHALF + 512) {
    int j = i - NHALF - 256;
    bpep[j] = bpe[((j & 31) << 3) + (j >> 5)];
  }
}

__global__ __launch_bounds__(256) void prep_dw(const float* s, const float* d,
                                               float* dw, float* fw, int N) {
  int n = blockIdx.x * 256 + threadIdx.x;
  if (n >= N) return;
  float dx = s[3*n] - d[3*n], dy = s[3*n+1] - d[3*n+1], dz = s[3*n+2] - d[3*n+2];
  float d2 = dx*dx + dy*dy + dz*dz;
  float w = expf(-0.5f * d2);
  dw[n] = w;
  fw[n] = w / (w + 1e-10f);   // == weights_avg.sum(axis=1) exactly
}

struct GP {
  const float* q; const float* e; const float* v; const float* rev;
  const _Float16* wsh;
  const float* be1; const float* be2; const float* bv;
  const float* bqp; const float* bpep;
  const float* dw; const float* fw;
  float* outb;
  int N; int SPLIT;
};

// MODE 0: h = relu(concat(q,e,rev,v) @ We1 + be1)   -> fp16 stash (baked) in d_out
// MODE 1: EF = (h @ We2 + be2) * dw                 -> fp32 out
// MODE 2: nb/2==0: qh -> xin(baked) ; ==1: eh -> xin ; ==2: x = fw*(v@Wv+bv)
// BK=128 single-buffered: halves barrier count vs BK=64 (stall is per-barrier
// fixed-cost; occupancy is register-capped at 2 waves/SIMD so 64 KB LDS is free).
template <int MODE>
__global__ __launch_bounds__(256) void gemm_k(GP p) {
  __shared__ __align__(16) _Float16 smh[2][16384];  // A=smh[0], B=smh[1] (each [128][128]); epilogue overlays
  __shared__ float biasL[128];
  __shared__ float scaleL[128];
  const int t = threadIdx.x;
  const int w = t >> 6, lane = t & 63, lr = lane & 15, lk = lane >> 4;
  // ---- XCD-aware bijective remap (grid.y padded %8==0; xcd = flat%8 owns a
  // contiguous mb chunk with its nb's consecutive -> A-panel reads hit ONE L2)
  const int NBX = (MODE == 1) ? 2 : 6;
  const int flat = blockIdx.y * NBX + blockIdx.x;
  const int xcd = flat & 7, kk2 = flat >> 3;
  const int CH = gridDim.y >> 3;
  const int nb = kk2 % NBX;
  const int mb = xcd * CH + kk2 / NBX;
  const int N = p.N, SPLIT = p.SPLIT;
  const int MT = (N + 127) >> 7;
  if (mb >= MT) return;
  const int wrow = (w >> 1) * 64, wcol = (w & 1) * 64;
  float* Xf  = p.outb;
  float* EFf = p.outb + (size_t)N * 256;
  float* PRf = p.outb + (size_t)N * 512;
  _Float16* hp1 = (_Float16*)Xf;     // h rows [0, SPLIT)
  _Float16* hp2 = (_Float16*)PRf;    // h rows [SPLIT, N) ; later xin lives here

  int K, KT; size_t boff; int g = 0, nbl = nb;
  if (MODE == 0)      { K = 1024; KT = 8; boff = (size_t)nb * 128 * 1024; }
  else if (MODE == 1) { K = 768;  KT = 6; boff = OFF_We2T + (size_t)nb * 128 * 768; }
  else { K = 256; KT = 2; g = nb >> 1; nbl = nb & 1;
         size_t wb = (g == 0) ? (size_t)OFF_WqT : (g == 1) ? (size_t)OFF_WpeT : (size_t)OFF_WvT;
         boff = wb + (size_t)nbl * 128 * 256; }
  const _Float16* Bt = p.wsh + boff;

  if (t < 128) {
    int gr = mb * 128 + t; if (gr > N - 1) gr = N - 1;
    if (MODE == 0) biasL[t] = p.be1[nb * 128 + t];
    else if (MODE == 1) { biasL[t] = p.be2[nb * 128 + t]; scaleL[t] = p.dw[gr]; }
    else {
      if (g == 0)      biasL[t] = p.bqp[nbl * 128 + t];
      else if (g == 1) biasL[t] = p.bpep[nbl * 128 + t];
      else { biasL[t] = p.bv[nbl * 128 + t]; scaleL[t] = p.fw[gr]; }
    }
  }

  // B tile [128 n][128 k] via direct-to-LDS 16B (weights pre-baked in ws)
  auto stageB = [&](int kt) {
#pragma unroll
    for (int i = 0; i < 8; ++i)
      gl_lds16(Bt + (size_t)(i * 16 + (t >> 4)) * K + kt * 128 + (t & 15) * 8,
               (char*)smh[1] + i * 4096 + w * 1024);
  };
  // MODE 1: h is pre-baked fp16 -> pure DMA staging
  auto stageA_dma = [&](int kt) {
    const _Float16* hr = (mb * 128 < SPLIT)
        ? hp1 + (size_t)mb * 128 * 768
        : hp2 + (size_t)(mb * 128 - SPLIT) * 768;
    int rmax = N - 1 - mb * 128;
#pragma unroll
    for (int i = 0; i < 8; ++i) {
      int rl = i * 16 + (t >> 4); if (rl > rmax) rl = rmax;
      gl_lds16(hr + (size_t)rl * 768 + kt * 128 + (t & 15) * 8,
               (char*)smh[0] + i * 4096 + w * 1024);
    }
  };
  // MODE 0/2: fp32 sources -> reg -> cvt -> swizzled ds_write. unroll 4 caps
  // in-flight float4s (VGPR discipline; r8's spill lesson).
  auto stageA_f32 = [&](int kt) {
    const float* As; int cc0;
    if (MODE == 0) {
      int gg = kt >> 1;   // concat: q (kt 0-1), e (2-3), rev (4-5), v (6-7)
      As = (gg == 0) ? p.q : (gg == 1) ? p.e : (gg == 2) ? p.rev : p.v;
      cc0 = (kt & 1) * 128;
    } else {
      As = (g == 0) ? p.q : (g == 1) ? p.e : p.v; cc0 = kt * 128;
    }
#pragma unroll 4
    for (int i = 0; i < 16; ++i) {
      int id = i * 256 + t, row = id >> 5, c4 = id & 31;
      int gr = mb * 128 + row; if (gr > N - 1) gr = N - 1;
      float4 fv = *(const float4*)(As + (size_t)gr * 256 + cc0 + c4 * 4);
      f16x4 hv; hv.x = (_Float16)fv.x; hv.y = (_Float16)fv.y;
      hv.z = (_Float16)fv.z; hv.w = (_Float16)fv.w;
      int off = row * 128 + ((c4 >> 4) << 6) +
                (((((c4 >> 1) & 7) ^ (row & 7)) << 3) | ((c4 & 1) << 2));
      *(f16x4*)(&smh[0][off]) = hv;
    }
  };

  f32x4 acc[4][4] = {};

  for (int kt = 0; kt < KT; ++kt) {
    if (MODE == 1) stageA_dma(kt); else stageA_f32(kt);
    stageB(kt);
    __syncthreads();                 // tile kt staged (full drain)
#pragma unroll
    for (int ks = 0; ks < 4; ++ks) {
      const int cb = (ks >> 1) << 6;            // which 64-half sub-block
      const int gq = (ks & 1) * 4 + lk;         // logical granule 0..7
      f16x8 af[4], bf[4];
#pragma unroll
      for (int i = 0; i < 4; ++i)
        af[i] = *(const f16x8*)(smh[0] + (wrow + i * 16 + lr) * 128 + cb + ((gq ^ (lr & 7)) << 3));
#pragma unroll
      for (int j = 0; j < 4; ++j)
        bf[j] = *(const f16x8*)(smh[1] + (wcol + j * 16 + lr) * 128 + cb + ((gq ^ (lr & 7)) << 3));
#pragma unroll
      for (int i = 0; i < 4; ++i)
#pragma unroll
        for (int j = 0; j < 4; ++j)
          acc[i][j] = __builtin_amdgcn_mfma_f32_16x16x32_f16(af[i], bf[j], acc[i][j], 0, 0, 0);
    }
    __syncthreads();                 // reads done before next stage overwrites
  }

  // ---------------- epilogue (LDS transpose for packed stores) ----------------
  const bool f16out = (MODE == 0) || (MODE == 2 && g < 2);
  if (f16out) {
    _Float16* Cl = (_Float16*)smh;  // [128][136] padded = 34816 B (fits in 64 KB arena)
#pragma unroll
    for (int i = 0; i < 4; ++i)
#pragma unroll
      for (int j = 0; j < 4; ++j)
#pragma unroll
        for (int ii = 0; ii < 4; ++ii) {
          int r = wrow + i * 16 + lk * 4 + ii, c = wcol + j * 16 + lr;
          float val = acc[i][j][ii] + biasL[c];
          if (MODE == 0) val = fmaxf(val, 0.f);
          Cl[r * 136 + c] = (_Float16)val;
        }
    __syncthreads();
#pragma unroll
    for (int i = 0; i < 8; ++i) {
      int id = i * 256 + t, row = id >> 4, ch = id & 15;
      int gr = mb * 128 + row;
      if (gr < N) {
        f16x8 val = *(const f16x8*)(Cl + row * 136 + ch * 8);
        if (MODE == 0) {
          // h stored BAKED: granule (ch&7) ^ (gr&7) within its 64-half block
          _Float16* hrow = (gr < SPLIT) ? hp1 + (size_t)gr * 768
                                        : hp2 + (size_t)(gr - SPLIT) * 768;
          int b64 = nb * 128 + ((ch >> 3) << 6);
          *(f16x8*)(hrow + b64 + (((ch ^ gr) & 7) << 3)) = val;
        } else {
          // xin stored BAKED for attn: row = gr*8+q, logical granule G at G^(q&7)
          int j0 = nbl * 128 + ch * 8;
          int q = j0 >> 5;                                   // 0..7
          int G = ((j0 >> 3) & 3) | ((g == 1) ? 4 : 0);
          *(f16x8*)(hp2 + ((size_t)gr * 8 + q) * 64 + (((G ^ q) & 7) << 3)) = val;
        }
      }
    }
  } else {
    float* Cf = (float*)smh;  // [64][132] padded = 33792 B, two passes
#pragma unroll
    for (int pp = 0; pp < 2; ++pp) {
      __syncthreads();
      if ((w >> 1) == pp) {
#pragma unroll
        for (int i = 0; i < 4; ++i)
#pragma unroll
          for (int j = 0; j < 4; ++j)
#pragma unroll
            for (int ii = 0; ii < 4; ++ii) {
              int rl = i * 16 + lk * 4 + ii, c = wcol + j * 16 + lr;
              Cf[rl * 132 + c] = (acc[i][j][ii] + biasL[c]) * scaleL[pp * 64 + rl];
            }
      }
      __syncthreads();
#pragma unroll
      for (int i = 0; i < 8; ++i) {
        int id = i * 256 + t, row = id >> 5, ch = id & 31;
        int gr = mb * 128 + pp * 64 + row;
        if (gr < N) {
          float4 val = *(const float4*)(Cf + row * 132 + ch * 4);
          float* dst = (MODE == 1) ? EFf + (size_t)gr * 256 + nb * 128 + ch * 4
                                   : Xf  + (size_t)gr * 256 + nbl * 128 + ch * 4;
          *(float4*)dst = val;
        }
      }
    }
  }
}

// per-head MLP + softmax; 64 (n,h)-rows per block; xin (baked) read & prob written in place
__global__ __launch_bounds__(256) void attn_k(GP p, const float* a1, const float* a2) {
  __shared__ __align__(16) char sm[28928];
  _Float16* xinl = (_Float16*)sm;            // [64][64] baked, later h2 (swizzled)
  _Float16* A1l  = (_Float16*)(sm + 8192);   // baked
  _Float16* A2l  = (_Float16*)(sm + 16384);  // baked
  float*    lg   = (float*)(sm + 20480);     // [64][33]
  const int t = threadIdx.x;
  const int w = t >> 6, lane = t & 63, lr = lane & 15, lk = lane >> 4;
  const int N = p.N;
  float* PRf = p.outb + (size_t)N * 512;
  const _Float16* xing = (const _Float16*)PRf;
  size_t rowbase = (size_t)blockIdx.x * 64;

#pragma unroll
  for (int i = 0; i < 2; ++i)
    gl_lds16(xing + (rowbase + i * 32 + (t >> 3)) * 64 + (t & 7) * 8,
             sm + i * 4096 + w * 1024);
#pragma unroll
  for (int i = 0; i < 2; ++i)
    gl_lds16(p.wsh + OFF_A1T + (size_t)(i * 32 + (t >> 3)) * 64 + (t & 7) * 8,
             sm + 8192 + i * 4096 + w * 1024);
  gl_lds16(p.wsh + OFF_A2T + (size_t)(t >> 3) * 64 + (t & 7) * 8,
           sm + 16384 + w * 1024);
  __syncthreads();

  f32x4 acc1[4] = {};
#pragma unroll
  for (int ks = 0; ks < 2; ++ks) {
    f16x8 a = *(const f16x8*)(xinl + (w * 16 + lr) * 64 + (((ks * 4 + lk) ^ (lr & 7)) << 3));
#pragma unroll
    for (int j = 0; j < 4; ++j) {
      f16x8 b = *(const f16x8*)(A1l + (j * 16 + lr) * 64 + (((ks * 4 + lk) ^ (lr & 7)) << 3));
      acc1[j] = __builtin_amdgcn_mfma_f32_16x16x32_f16(a, b, acc1[j], 0, 0, 0);
    }
  }
  __syncthreads();   // xinl reads done; overwrite with h2 (swizzled store)
#pragma unroll
  for (int j = 0; j < 4; ++j) {
    float bb = a1[j * 16 + lr];
#pragma unroll
    for (int ii = 0; ii < 4; ++ii) {
      float hv = fmaxf(acc1[j][ii] + bb, 0.f);
      int row2 = w * 16 + lk * 4 + ii, col = j * 16 + lr;
      xinl[row2 * 64 + (((((col >> 3) ^ row2) & 7) << 3) | (col & 7))] = (_Float16)hv;
    }
  }
  __syncthreads();
  f32x4 acc2[2] = {};
#pragma unroll
  for (int ks = 0; ks < 2; ++ks) {
    f16x8 a = *(const f16x8*)(xinl + (w * 16 + lr) * 64 + (((ks * 4 + lk) ^ (lr & 7)) << 3));
#pragma unroll
    for (int j = 0; j < 2; ++j) {
      f16x8 b = *(const f16x8*)(A2l + (j * 16 + lr) * 64 + (((ks * 4 + lk) ^ (lr & 7)) << 3));
      acc2[j] = __builtin_amdgcn_mfma_f32_16x16x32_f16(a, b, acc2[j], 0, 0, 0);
    }
  }
#pragma unroll
  for (int j = 0; j < 2; ++j) {
    float bb = a2[j * 16 + lr];
#pragma unroll
    for (int ii = 0; ii < 4; ++ii)
      lg[(w * 16 + lk * 4 + ii) * 33 + j * 16 + lr] = acc2[j][ii] + bb;
  }
  __syncthreads();
  {   // softmax over 32 channels; 4 lanes per row
    int r = t >> 2, pq = t & 3;
    float vv[8];
#pragma unroll
    for (int jj = 0; jj < 8; ++jj) vv[jj] = lg[r * 33 + pq * 8 + jj];
    float mx = vv[0];
#pragma unroll
    for (int jj = 1; jj < 8; ++jj) mx = fmaxf(mx, vv[jj]);
    mx = fmaxf(mx, __shfl_xor(mx, 1));
    mx = fmaxf(mx, __shfl_xor(mx, 2));
    float s = 0.f;
#pragma unroll
    for (int jj = 0; jj < 8; ++jj) { vv[jj] = __expf(vv[jj] - mx); s += vv[jj]; }
    s += __shfl_xor(s, 1);
    s += __shfl_xor(s, 2);
    float inv = 1.f / s;
#pragma unroll
    for (int jj = 0; jj < 8; ++jj) lg[r * 33 + pq * 8 + jj] = vv[jj] * inv;
  }
  __syncthreads();
  // write prob[n][o][h] coalesced (address == rowbase*32 + id, fully linear)
#pragma unroll
  for (int i = 0; i < 8; ++i) {
    int id = i * 256 + t; int hh = id & 7, o = (id >> 3) & 31, nl = id >> 8;
    PRf[(rowbase / 8 + nl) * 256 + o * 8 + hh] = lg[(nl * 8 + hh) * 33 + o];
  }
}

extern "C" void kernel_launch(void* const* d_in, const int* in_sizes, int n_in,
                              void* d_out, int out_size, void* d_ws, size_t ws_size,
                              hipStream_t stream) {
  const float* query = (const float*)d_in[0];
  const float* edge  = (const float*)d_in[1];
  const float* value = (const float*)d_in[2];
  const float* rev   = (const float*)d_in[3];
  const float* srcc  = (const float*)d_in[4];
  const float* dstc  = (const float*)d_in[5];
  const float* We1 = (const float*)d_in[6];  const float* be1 = (const float*)d_in[7];
  const float* We2 = (const float*)d_in[8];  const float* be2 = (const float*)d_in[9];
  const float* Wq  = (const float*)d_in[10]; const float* bq  = (const float*)d_in[11];
  const float* Wpe = (const float*)d_in[12]; const float* bpe = (const float*)d_in[13];
  const float* Wv  = (const float*)d_in[14]; const float* bv  = (const float*)d_in[15];
  const float* A1  = (const float*)d_in[16]; const float* a1  = (const float*)d_in[17];
  const float* A2  = (const float*)d_in[18]; const float* a2  = (const float*)d_in[19];
  const int N = in_sizes[0] / 256;           // 120000

  _Float16* wsh = (_Float16*)d_ws;
  float* wsf = (float*)d_ws;
  float* dwA  = wsf + NHALF / 2;
  float* fwA  = dwA + N;
  float* bqp  = fwA + N;
  float* bpep = bqp + 256;

  prep_weights<<<(NHALF + 512 + 255) / 256, 256, 0, stream>>>(
      We1, We2, Wq, Wpe, Wv, A1, A2, bq, bpe, wsh, bqp, bpep);
  prep_dw<<<(N + 255) / 256, 256, 0, stream>>>(srcc, dstc, dwA, fwA, N);

  GP p;
  p.q = query; p.e = edge; p.v = value; p.rev = rev;
  p.wsh = wsh; p.be1 = be1; p.be2 = be2; p.bv = bv;
  p.bqp = bqp; p.bpep = bpep; p.dw = dwA; p.fw = fwA;
  p.outb = (float*)d_out; p.N = N; p.SPLIT = (N * 2) / 3;

  const int MT = (N + 127) >> 7;             // 938
  const int MTP = (MT + 7) & ~7;             // 944: grid %8==0 for XCD remap
  gemm_k<0><<<dim3(6, MTP), 256, 0, stream>>>(p);   // h (fp16 baked, stashed in d_out)
  gemm_k<1><<<dim3(2, MTP), 256, 0, stream>>>(p);   // edge_feature
  gemm_k<2><<<dim3(6, MTP), 256, 0, stream>>>(p);   // x  +  xin (qh|eh, baked)
  attn_k<<<N / 8, 256, 0, stream>>>(p, a1, a2);     // prob
}

// Round 11
// 1140.024 us; speedup vs baseline: 1.4559x; 1.1136x over previous
//
#include <hip/hip_runtime.h>
#include <stdint.h>

typedef float  f32x4 __attribute__((ext_vector_type(4)));
typedef _Float16 f16x8 __attribute__((ext_vector_type(8)));
typedef _Float16 f16x4 __attribute__((ext_vector_type(4)));

// ws layout (half units)
#define OFF_We1T 0          // [768][1024]  (k baked)
#define OFF_We2T 786432     // [256][768]   (k baked)
#define OFF_WqT  983040     // [256][256] head-permuted cols, k baked
#define OFF_WpeT 1048576    // [256][256] head-permuted cols, k baked
#define OFF_WvT  1114112    // [256][256]   (k baked)
#define OFF_A1T  1179648    // [64][64]     (k baked)
#define OFF_A2T  1183744    // [32][64]     (k baked)
#define NHALF    1185792

__device__ __forceinline__ void gl_lds16(const void* g, void* l) {
  __builtin_amdgcn_global_load_lds((const __attribute__((address_space(1))) uint32_t*)g,
                                   (__attribute__((address_space(3))) uint32_t*)l, 16, 0, 0);
}

// 16B-granule XOR swizzle within each 64-half K-block: stored granule =
// logical granule ^ (row&7). Involution; baked into weight/h/xin storage so
// linear global_load_lds lands pre-swizzled; MFMA reads XOR with (row&7).
__device__ __forceinline__ int bake(int k, int n) {
  return (k & ~63) | ((((k >> 3) ^ n) & 7) << 3) | (k & 7);
}

// LDS-tiled transpose for the two big weight matrices (coalesced reads AND writes;
// the old strided path over-fetched ~64x on We1/We2).
__global__ __launch_bounds__(256) void prep_tr(const float* We1, const float* We2,
                                               _Float16* wsh) {
  __shared__ float ldsf[64 * 65];
  int tile = blockIdx.x;
  const float* src; _Float16* dst; int W, Ksrc, tk, tn;
  if (tile < 192) { src = We1; dst = wsh + OFF_We1T; W = 768; Ksrc = 1024; tk = tile / 12; tn = tile % 12; }
  else { tile -= 192; src = We2; dst = wsh + OFF_We2T; W = 256; Ksrc = 768; tk = tile / 4; tn = tile % 4; }
  const int t = threadIdx.x;
#pragma unroll
  for (int i = 0; i < 16; ++i) {
    int id = i * 256 + t, r = id >> 6, c = id & 63;
    ldsf[r * 65 + c] = src[(size_t)(tk * 64 + r) * W + tn * 64 + c];
  }
  __syncthreads();
#pragma unroll
  for (int i = 0; i < 2; ++i) {
    int id = i * 256 + t, nl = id >> 3, g = id & 7;
    int ng = tn * 64 + nl;
    int gs = g ^ (ng & 7);                 // bake: stored granule g holds src granule g^(n&7)
    f16x8 v;
#pragma unroll
    for (int e = 0; e < 8; ++e) v[e] = (_Float16)ldsf[(gs * 8 + e) * 65 + nl];
    *(f16x8*)(dst + (size_t)ng * Ksrc + tk * 64 + g * 8) = v;
  }
}

// small matrices + bias permutes (tiny; strided reads OK)
__global__ __launch_bounds__(256) void prep_weights(
    const float* Wq, const float* Wpe, const float* Wv,
    const float* A1, const float* A2, const float* bq, const float* bpe,
    _Float16* wsh, float* bqp, float* bpep) {
  int i = OFF_WqT + blockIdx.x * 256 + threadIdx.x;
  if (i < OFF_WpeT) {                       // WqT' : col n=h*32+c <- src col c*8+h
    int j = i - OFF_WqT; int n = j >> 8, k = j & 255;
    int sc = ((n & 31) << 3) + (n >> 5);
    wsh[i] = (_Float16)Wq[bake(k, n) * 256 + sc];
  } else if (i < OFF_WvT) {
    int j = i - OFF_WpeT; int n = j >> 8, k = j & 255;
    int sc = ((n & 31) << 3) + (n >> 5);
    wsh[i] = (_Float16)Wpe[bake(k, n) * 256 + sc];
  } else if (i < OFF_A1T) {
    int j = i - OFF_WvT; int n = j >> 8, k = j & 255;
    wsh[i] = (_Float16)Wv[bake(k, n) * 256 + n];
  } else if (i < OFF_A2T) {                 // A1T[o][c] = A1[bake(c)][o]
    int j = i - OFF_A1T; int o = j >> 6, c = j & 63;
    wsh[i] = (_Float16)A1[bake(c, o) * 64 + o];
  } else if (i < NHALF) {                   // A2T[o][c] = A2[bake(c)][o]
    int j = i - OFF_A2T; int o = j >> 6, c = j & 63;
    wsh[i] = (_Float16)A2[bake(c, o) * 32 + o];
  } else if (i < NHALF + 256) {
    int j = i - NHALF;
    bqp[j] = bq[((j & 31) << 3) + (j >> 5)];
  } else if (i < NHALF + 512) {
    int j = i - NHALF - 256;
    bpep[j] = bpe[((j & 31) << 3) + (j >> 5)];
  }
}

__global__ __launch_bounds__(256) void prep_dw(const float* s, const float* d,
                                               float* dw, float* fw, int N) {
  int n = blockIdx.x * 256 + threadIdx.x;
  if (n >= N) return;
  float dx = s[3*n] - d[3*n], dy = s[3*n+1] - d[3*n+1], dz = s[3*n+2] - d[3*n+2];
  float d2 = dx*dx + dy*dy + dz*dz;
  float w = expf(-0.5f * d2);
  dw[n] = w;
  fw[n] = w / (w + 1e-10f);   // == weights_avg.sum(axis=1) exactly
}

struct GP {
  const float* q; const float* e; const float* v; const float* rev;
  const _Float16* wsh;
  const float* be1; const float* be2; const float* bv;
  const float* bqp; const float* bpep;
  const float* dw; const float* fw;
  float* outb;
  int N; int SPLIT;
};

// 512 threads, 8 waves in 2x4 grid; per-wave output 64x32 -> acc = 32 VGPR.
// Total regs (arch+acc) targeted <= 128 => 4 waves/SIMD (16 waves/CU) WITHOUT spill.
// BK=64 single-buffered (2 barriers/K-step); granule-XOR bake kills bank conflicts.
template <int MODE>
__global__ __launch_bounds__(512, 4) void gemm_k(GP p) {
  __shared__ __align__(16) char arena[34816];   // A[0,16K) B[16K,32K); epilogue overlays
  __shared__ float biasL[128];
  __shared__ float scaleL[128];
  const int t = threadIdx.x;
  const int w = t >> 6, lane = t & 63, lr = lane & 15, lk = lane >> 4;
  const int wrow = (w >> 2) * 64, wcol = (w & 3) * 32;
  // ---- XCD-aware bijective remap (grid.y padded %8==0)
  const int NBX = (MODE == 1) ? 2 : 6;
  const int flat = blockIdx.y * NBX + blockIdx.x;
  const int xcd = flat & 7, kk2 = flat >> 3;
  const int CH = gridDim.y >> 3;
  const int nb = kk2 % NBX;
  const int mb = xcd * CH + kk2 / NBX;
  const int N = p.N, SPLIT = p.SPLIT;
  const int MT = (N + 127) >> 7;
  if (mb >= MT) return;
  float* Xf  = p.outb;
  float* EFf = p.outb + (size_t)N * 256;
  float* PRf = p.outb + (size_t)N * 512;
  _Float16* hp1 = (_Float16*)Xf;     // h rows [0, SPLIT)
  _Float16* hp2 = (_Float16*)PRf;    // h rows [SPLIT, N) ; later xin lives here

  int K, KT; size_t boff; int g = 0, nbl = nb;
  if (MODE == 0)      { K = 1024; KT = 16; boff = (size_t)nb * 128 * 1024; }
  else if (MODE == 1) { K = 768;  KT = 12; boff = OFF_We2T + (size_t)nb * 128 * 768; }
  else { K = 256; KT = 4; g = nb >> 1; nbl = nb & 1;
         size_t wb = (g == 0) ? (size_t)OFF_WqT : (g == 1) ? (size_t)OFF_WpeT : (size_t)OFF_WvT;
         boff = wb + (size_t)nbl * 128 * 256; }
  const _Float16* Bt = p.wsh + boff;

  if (t < 128) {
    int gr = mb * 128 + t; if (gr > N - 1) gr = N - 1;
    if (MODE == 0) biasL[t] = p.be1[nb * 128 + t];
    else if (MODE == 1) { biasL[t] = p.be2[nb * 128 + t]; scaleL[t] = p.dw[gr]; }
    else {
      if (g == 0)      biasL[t] = p.bqp[nbl * 128 + t];
      else if (g == 1) biasL[t] = p.bpep[nbl * 128 + t];
      else { biasL[t] = p.bv[nbl * 128 + t]; scaleL[t] = p.fw[gr]; }
    }
  }

  auto stageB = [&](int kt) {
#pragma unroll
    for (int i = 0; i < 2; ++i)
      gl_lds16(Bt + (size_t)(i * 64 + (t >> 3)) * K + kt * 64 + (t & 7) * 8,
               arena + 16384 + i * 8192 + (t >> 6) * 1024);
  };
  auto stageA_dma = [&](int kt) {   // MODE 1: h is pre-baked fp16 -> pure DMA
    const _Float16* hr = (mb * 128 < SPLIT)
        ? hp1 + (size_t)mb * 128 * 768
        : hp2 + (size_t)(mb * 128 - SPLIT) * 768;
    int rmax = N - 1 - mb * 128;
#pragma unroll
    for (int i = 0; i < 2; ++i) {
      int rl = i * 64 + (t >> 3); if (rl > rmax) rl = rmax;
      gl_lds16(hr + (size_t)rl * 768 + kt * 64 + (t & 7) * 8,
               arena + i * 8192 + (t >> 6) * 1024);
    }
  };
  auto loadA = [&](int kt, float4* pre) {    // fp32 sources: issue early
    const float* As; int cc0;
    if (MODE == 0) {
      int gg = kt >> 2;   // concat: query, edge, reverse_edge, value
      As = (gg == 0) ? p.q : (gg == 1) ? p.e : (gg == 2) ? p.rev : p.v;
      cc0 = (kt & 3) * 64;
    } else {
      As = (g == 0) ? p.q : (g == 1) ? p.e : p.v; cc0 = kt * 64;
    }
#pragma unroll
    for (int i = 0; i < 4; ++i) {
      int id = i * 512 + t, row = id >> 4, c4 = id & 15;
      int gr = mb * 128 + row; if (gr > N - 1) gr = N - 1;
      pre[i] = *(const float4*)(As + (size_t)gr * 256 + cc0 + c4 * 4);
    }
  };
  auto writeA = [&](const float4* pre) {  // cvt + swizzled ds_write
#pragma unroll
    for (int i = 0; i < 4; ++i) {
      int id = i * 512 + t, row = id >> 4, c4 = id & 15;
      f16x4 hv; hv.x = (_Float16)pre[i].x; hv.y = (_Float16)pre[i].y;
      hv.z = (_Float16)pre[i].z; hv.w = (_Float16)pre[i].w;
      int off = row * 64 + (((((c4 >> 1) ^ row) & 7) << 3) | ((c4 & 1) << 2));
      *(f16x4*)((_Float16*)arena + off) = hv;
    }
  };

  f32x4 acc[4][2] = {};
  float4 pre[4];
  if (MODE == 1) stageA_dma(0);
  else { loadA(0, pre); writeA(pre); }
  stageB(0);
  __syncthreads();

  const _Float16* Ab = (const _Float16*)arena;
  const _Float16* Bb = (const _Float16*)(arena + 16384);
  for (int kt = 0; kt < KT; ++kt) {
    const bool more = (kt + 1 < KT);
    if (more && MODE != 1) loadA(kt + 1, pre);   // fire next A loads before MFMAs
#pragma unroll
    for (int ks = 0; ks < 2; ++ks) {
      const int gq = ks * 4 + lk;
      f16x8 af[4], bf[2];
#pragma unroll
      for (int i = 0; i < 4; ++i)
        af[i] = *(const f16x8*)(Ab + (wrow + i * 16 + lr) * 64 + ((gq ^ (lr & 7)) << 3));
#pragma unroll
      for (int j = 0; j < 2; ++j)
        bf[j] = *(const f16x8*)(Bb + (wcol + j * 16 + lr) * 64 + ((gq ^ (lr & 7)) << 3));
#pragma unroll
      for (int i = 0; i < 4; ++i)
#pragma unroll
        for (int j = 0; j < 2; ++j)
          acc[i][j] = __builtin_amdgcn_mfma_f32_16x16x32_f16(af[i], bf[j], acc[i][j], 0, 0, 0);
    }
    if (more) {
      __syncthreads();                 // reads of tile kt done
      if (MODE == 1) stageA_dma(kt + 1);
      else writeA(pre);                // loads had the MFMA phase to land
      stageB(kt + 1);
      __syncthreads();                 // tile kt+1 visible
    }
  }
  __syncthreads();   // protect arena reuse by epilogue

  // ---------------- epilogue (LDS transpose for packed stores) ----------------
  const bool f16out = (MODE == 0) || (MODE == 2 && g < 2);
  if (f16out) {
    _Float16* Cl = (_Float16*)arena;  // [128][136] padded = 34816 B exact
#pragma unroll
    for (int i = 0; i < 4; ++i)
#pragma unroll
      for (int j = 0; j < 2; ++j)
#pragma unroll
        for (int ii = 0; ii < 4; ++ii) {
          int r = wrow + i * 16 + lk * 4 + ii, c = wcol + j * 16 + lr;
          float val = acc[i][j][ii] + biasL[c];
          if (MODE == 0) val = fmaxf(val, 0.f);
          Cl[r * 136 + c] = (_Float16)val;
        }
    __syncthreads();
#pragma unroll
    for (int i = 0; i < 4; ++i) {
      int id = i * 512 + t, row = id >> 4, ch = id & 15;
      int gr = mb * 128 + row;
      if (gr < N) {
        f16x8 val = *(const f16x8*)(Cl + row * 136 + ch * 8);
        if (MODE == 0) {
          // h stored BAKED: granule (ch&7) ^ (gr&7) within its 64-half block
          _Float16* hrow = (gr < SPLIT) ? hp1 + (size_t)gr * 768
                                        : hp2 + (size_t)(gr - SPLIT) * 768;
          int b64 = nb * 128 + ((ch >> 3) << 6);
          *(f16x8*)(hrow + b64 + (((ch ^ gr) & 7) << 3)) = val;
        } else {
          // xin stored BAKED for attn: row = gr*8+q, logical granule G at G^(q&7)
          int j0 = nbl * 128 + ch * 8;
          int q = j0 >> 5;                                   // 0..7
          int G = ((j0 >> 3) & 3) | ((g == 1) ? 4 : 0);
          *(f16x8*)(hp2 + ((size_t)gr * 8 + q) * 64 + (((G ^ q) & 7) << 3)) = val;
        }
      }
    }
  } else {
    float* Cf = (float*)arena;  // [64][132] padded = 33792 B, two passes
#pragma unroll
    for (int pp = 0; pp < 2; ++pp) {
      __syncthreads();
      if ((w >> 2) == pp) {
#pragma unroll
        for (int i = 0; i < 4; ++i)
#pragma unroll
          for (int j = 0; j < 2; ++j)
#pragma unroll
            for (int ii = 0; ii < 4; ++ii) {
              int rl = i * 16 + lk * 4 + ii, c = wcol + j * 16 + lr;
              Cf[rl * 132 + c] = (acc[i][j][ii] + biasL[c]) * scaleL[pp * 64 + rl];
            }
      }
      __syncthreads();
#pragma unroll
      for (int i = 0; i < 4; ++i) {
        int id = i * 512 + t, row = id >> 5, ch = id & 31;
        int gr = mb * 128 + pp * 64 + row;
        if (gr < N) {
          float4 val = *(const float4*)(Cf + row * 132 + ch * 4);
          float* dst = (MODE == 1) ? EFf + (size_t)gr * 256 + nb * 128 + ch * 4
                                   : Xf  + (size_t)gr * 256 + nbl * 128 + ch * 4;
          *(float4*)dst = val;
        }
      }
    }
  }
}

// per-head MLP + softmax; 64 (n,h)-rows per block; xin (baked) read & prob written in place
__global__ __launch_bounds__(256) void attn_k(GP p, const float* a1, const float* a2) {
  __shared__ __align__(16) char sm[28928];
  _Float16* xinl = (_Float16*)sm;            // [64][64] baked, later h2 (swizzled)
  _Float16* A1l  = (_Float16*)(sm + 8192);   // baked
  _Float16* A2l  = (_Float16*)(sm + 16384);  // baked
  float*    lg   = (float*)(sm + 20480);     // [64][33]
  const int t = threadIdx.x;
  const int w = t >> 6, lane = t & 63, lr = lane & 15, lk = lane >> 4;
  const int N = p.N;
  float* PRf = p.outb + (size_t)N * 512;
  const _Float16* xing = (const _Float16*)PRf;
  size_t rowbase = (size_t)blockIdx.x * 64;

#pragma unroll
  for (int i = 0; i < 2; ++i)
    gl_lds16(xing + (rowbase + i * 32 + (t >> 3)) * 64 + (t & 7) * 8,
             sm + i * 4096 + w * 1024);
#pragma unroll
  for (int i = 0; i < 2; ++i)
    gl_lds16(p.wsh + OFF_A1T + (size_t)(i * 32 + (t >> 3)) * 64 + (t & 7) * 8,
             sm + 8192 + i * 4096 + w * 1024);
  gl_lds16(p.wsh + OFF_A2T + (size_t)(t >> 3) * 64 + (t & 7) * 8,
           sm + 16384 + w * 1024);
  __syncthreads();

  f32x4 acc1[4] = {};
#pragma unroll
  for (int ks = 0; ks < 2; ++ks) {
    f16x8 a = *(const f16x8*)(xinl + (w * 16 + lr) * 64 + (((ks * 4 + lk) ^ (lr & 7)) << 3));
#pragma unroll
    for (int j = 0; j < 4; ++j) {
      f16x8 b = *(const f16x8*)(A1l + (j * 16 + lr) * 64 + (((ks * 4 + lk) ^ (lr & 7)) << 3));
      acc1[j] = __builtin_amdgcn_mfma_f32_16x16x32_f16(a, b, acc1[j], 0, 0, 0);
    }
  }
  __syncthreads();   // xinl reads done; overwrite with h2 (swizzled store)
#pragma unroll
  for (int j = 0; j < 4; ++j) {
    float bb = a1[j * 16 + lr];
#pragma unroll
    for (int ii = 0; ii < 4; ++ii) {
      float hv = fmaxf(acc1[j][ii] + bb, 0.f);
      int row2 = w * 16 + lk * 4 + ii, col = j * 16 + lr;
      xinl[row2 * 64 + (((((col >> 3) ^ row2) & 7) << 3) | (col & 7))] = (_Float16)hv;
    }
  }
  __syncthreads();
  f32x4 acc2[2] = {};
#pragma unroll
  for (int ks = 0; ks < 2; ++ks) {
    f16x8 a = *(const f16x8*)(xinl + (w * 16 + lr) * 64 + (((ks * 4 + lk) ^ (lr & 7)) << 3));
#pragma unroll
    for (int j = 0; j < 2; ++j) {
      f16x8 b = *(const f16x8*)(A2l + (j * 16 + lr) * 64 + (((ks * 4 + lk) ^ (lr & 7)) << 3));
      acc2[j] = __builtin_amdgcn_mfma_f32_16x16x32_f16(a, b, acc2[j], 0, 0, 0);
    }
  }
#pragma unroll
  for (int j = 0; j < 2; ++j) {
    float bb = a2[j * 16 + lr];
#pragma unroll
    for (int ii = 0; ii < 4; ++ii)
      lg[(w * 16 + lk * 4 + ii) * 33 + j * 16 + lr] = acc2[j][ii] + bb;
  }
  __syncthreads();
  {   // softmax over 32 channels; 4 lanes per row
    int r = t >> 2, pq = t & 3;
    float vv[8];
#pragma unroll
    for (int jj = 0; jj < 8; ++jj) vv[jj] = lg[r * 33 + pq * 8 + jj];
    float mx = vv[0];
#pragma unroll
    for (int jj = 1; jj < 8; ++jj) mx = fmaxf(mx, vv[jj]);
    mx = fmaxf(mx, __shfl_xor(mx, 1));
    mx = fmaxf(mx, __shfl_xor(mx, 2));
    float s = 0.f;
#pragma unroll
    for (int jj = 0; jj < 8; ++jj) { vv[jj] = __expf(vv[jj] - mx); s += vv[jj]; }
    s += __shfl_xor(s, 1);
    s += __shfl_xor(s, 2);
    float inv = 1.f / s;
#pragma unroll
    for (int jj = 0; jj < 8; ++jj) lg[r * 33 + pq * 8 + jj] = vv[jj] * inv;
  }
  __syncthreads();
  // write prob[n][o][h] coalesced (address == rowbase*32 + id, fully linear)
#pragma unroll
  for (int i = 0; i < 8; ++i) {
    int id = i * 256 + t; int hh = id & 7, o = (id >> 3) & 31, nl = id >> 8;
    PRf[(rowbase / 8 + nl) * 256 + o * 8 + hh] = lg[(nl * 8 + hh) * 33 + o];
  }
}

extern "C" void kernel_launch(void* const* d_in, const int* in_sizes, int n_in,
                              void* d_out, int out_size, void* d_ws, size_t ws_size,
                              hipStream_t stream) {
  const float* query = (const float*)d_in[0];
  const float* edge  = (const float*)d_in[1];
  const float* value = (const float*)d_in[2];
  const float* rev   = (const float*)d_in[3];
  const float* srcc  = (const float*)d_in[4];
  const float* dstc  = (const float*)d_in[5];
  const float* We1 = (const float*)d_in[6];  const float* be1 = (const float*)d_in[7];
  const float* We2 = (const float*)d_in[8];  const float* be2 = (const float*)d_in[9];
  const float* Wq  = (const float*)d_in[10]; const float* bq  = (const float*)d_in[11];
  const float* Wpe = (const float*)d_in[12]; const float* bpe = (const float*)d_in[13];
  const float* Wv  = (const float*)d_in[14]; const float* bv  = (const float*)d_in[15];
  const float* A1  = (const float*)d_in[16]; const float* a1  = (const float*)d_in[17];
  const float* A2  = (const float*)d_in[18]; const float* a2  = (const float*)d_in[19];
  const int N = in_sizes[0] / 256;           // 120000

  _Float16* wsh = (_Float16*)d_ws;
  float* wsf = (float*)d_ws;
  float* dwA  = wsf + NHALF / 2;
  float* fwA  = dwA + N;
  float* bqp  = fwA + N;
  float* bpep = bqp + 256;

  prep_tr<<<240, 256, 0, stream>>>(We1, We2, wsh);
  prep_weights<<<794, 256, 0, stream>>>(Wq, Wpe, Wv, A1, A2, bq, bpe, wsh, bqp, bpep);
  prep_dw<<<(N + 255) / 256, 256, 0, stream>>>(srcc, dstc, dwA, fwA, N);

  GP p;
  p.q = query; p.e = edge; p.v = value; p.rev = rev;
  p.wsh = wsh; p.be1 = be1; p.be2 = be2; p.bv = bv;
  p.bqp = bqp; p.bpep = bpep; p.dw = dwA; p.fw = fwA;
  p.outb = (float*)d_out; p.N = N; p.SPLIT = (N * 2) / 3;

  const int MT = (N + 127) >> 7;             // 938
  const int MTP = (MT + 7) & ~7;             // 944: grid %8==0 for XCD remap
  gemm_k<0><<<dim3(6, MTP), 512, 0, stream>>>(p);   // h (fp16 baked, stashed in d_out)
  gemm_k<1><<<dim3(2, MTP), 512, 0, stream>>>(p);   // edge_feature
  gemm_k<2><<<dim3(6, MTP), 512, 0, stream>>>(p);   // x  +  xin (qh|eh, baked)
  attn_k<<<N / 8, 256, 0, stream>>>(p, a1, a2);     // prob
}